// Round 2
// baseline (2885.530 us; speedup 1.0000x reference)
//
#include <hip/hip_runtime.h>

#define NNODES 100000
#define NEDGES 1600000
#define NCOUP  800000
#define D      32
#define DE     65
#define JP     68   // padded hidden dim (multiple of 4, 16B-aligned rows)
#define KP     37   // padded k-stride for precompute LDS (conflict-free)
#define W1_LD  68

__device__ __forceinline__ float selu_f(float x) {
    const float scale = 1.0507009873554805f;
    const float alpha = 1.6732632423543772f;
    return x > 0.0f ? scale * x : scale * alpha * (__expf(x) - 1.0f);
}

// A[n][j] = b1[j] + sum_k h[n][k] * W1[k][j]          (k in [0,32))
// B[n][j] =          sum_k h[n][k] * W1[32+k][j]
__global__ __launch_bounds__(256) void node_precompute(
    const float* __restrict__ h, const float* __restrict__ W1,
    const float* __restrict__ b1,
    float* __restrict__ A, float* __restrict__ B)
{
    __shared__ float sWA[JP * KP];   // [j][k] transposed
    __shared__ float sWB[JP * KP];
    __shared__ float sb1[JP];
    for (int i = threadIdx.x; i < JP * 32; i += 256) {
        int j = i >> 5, k = i & 31;
        sWA[j * KP + k] = (j < DE) ? W1[k * DE + j] : 0.f;
        sWB[j * KP + k] = (j < DE) ? W1[(k + 32) * DE + j] : 0.f;
    }
    if (threadIdx.x < JP) sb1[threadIdx.x] = (threadIdx.x < DE) ? b1[threadIdx.x] : 0.f;
    __syncthreads();

    const int idx = blockIdx.x * 256 + threadIdx.x;
    const int n = idx / JP;
    const int j = idx - n * JP;
    if (n >= NNODES) return;
    const float4* hr = reinterpret_cast<const float4*>(h + (size_t)n * D);
    const float* wa = &sWA[j * KP];
    const float* wb = &sWB[j * KP];
    float a = sb1[j], b = 0.f;
    #pragma unroll
    for (int kk = 0; kk < 8; ++kk) {
        float4 hv = hr[kk];
        a = fmaf(hv.x, wa[4*kk+0], a); a = fmaf(hv.y, wa[4*kk+1], a);
        a = fmaf(hv.z, wa[4*kk+2], a); a = fmaf(hv.w, wa[4*kk+3], a);
        b = fmaf(hv.x, wb[4*kk+0], b); b = fmaf(hv.y, wb[4*kk+1], b);
        b = fmaf(hv.z, wb[4*kk+2], b); b = fmaf(hv.w, wb[4*kk+3], b);
    }
    A[(size_t)n * JP + j] = a;
    B[(size_t)n * JP + j] = b;
}

__global__ __launch_bounds__(256) void edge_kernel(
    const float* __restrict__ A, const float* __restrict__ B,
    const float* __restrict__ coup,
    const float* __restrict__ W1, const float* __restrict__ W2,
    const float* __restrict__ b2,
    const int* __restrict__ senders, const int* __restrict__ receivers,
    float* __restrict__ out)
{
    __shared__ float sW2[JP * D];    // [j][d], rows j>=65 zero
    __shared__ float sw1c[JP];
    __shared__ float sb2[D];
    for (int i = threadIdx.x; i < JP * D; i += 256) {
        int j = i >> 5;
        sW2[i] = (j < DE) ? W2[j * D + (i & 31)] : 0.f;
    }
    if (threadIdx.x < JP) sw1c[threadIdx.x] = (threadIdx.x < DE) ? W1[64 * DE + threadIdx.x] : 0.f;
    if (threadIdx.x >= 128 && threadIdx.x < 128 + D) sb2[threadIdx.x - 128] = b2[threadIdx.x - 128];
    __syncthreads();

    const int e = blockIdx.x * 256 + threadIdx.x;   // grid covers exactly NEDGES
    const int s = senders[e];
    const int r = receivers[e];
    const float c = coup[e < NCOUP ? e : e - NCOUP];

    const float4* Ar = reinterpret_cast<const float4*>(A + (size_t)r * JP);
    const float4* Bs = reinterpret_cast<const float4*>(B + (size_t)s * JP);
    const float4* w1c4 = reinterpret_cast<const float4*>(sw1c);

    float acc[D];
    #pragma unroll
    for (int d2 = 0; d2 < D; ++d2) acc[d2] = sb2[d2];

    #pragma unroll 1
    for (int jg = 0; jg < JP / 4; ++jg) {
        float4 av = Ar[jg];
        float4 bv = Bs[jg];
        float4 wv = w1c4[jg];
        float h0 = selu_f(fmaf(c, wv.x, av.x + bv.x));
        float h1 = selu_f(fmaf(c, wv.y, av.y + bv.y));
        float h2 = selu_f(fmaf(c, wv.z, av.z + bv.z));
        float h3 = selu_f(fmaf(c, wv.w, av.w + bv.w));
        const float* w2r = &sW2[(jg * 4) * D];
        #pragma unroll
        for (int d2 = 0; d2 < D; ++d2) {
            float t = fmaf(h0, w2r[d2], acc[d2]);
            t = fmaf(h1, w2r[D + d2], t);
            t = fmaf(h2, w2r[2 * D + d2], t);
            acc[d2] = fmaf(h3, w2r[3 * D + d2], t);
        }
    }

    float* op = out + (size_t)r * D;
    #pragma unroll
    for (int d2 = 0; d2 < D; ++d2) unsafeAtomicAdd(op + d2, selu_f(acc[d2]));
}

// ---------------- fallback path (ws too small): round-1 monolithic kernel ----
__global__ __launch_bounds__(256) void edge_msg_fallback(
    const float* __restrict__ h, const float* __restrict__ coup,
    const float* __restrict__ W1, const float* __restrict__ b1,
    const float* __restrict__ W2, const float* __restrict__ b2,
    const int* __restrict__ senders, const int* __restrict__ receivers,
    float* __restrict__ out)
{
    __shared__ float sW1t[DE * W1_LD];
    __shared__ float sW2[DE * D];
    __shared__ float sb1[DE];
    __shared__ float sb2[D];
    for (int i = threadIdx.x; i < DE * DE; i += 256) {
        int k = i / DE, j = i - k * DE;
        sW1t[j * W1_LD + k] = W1[i];
    }
    for (int i = threadIdx.x; i < DE * D; i += 256) sW2[i] = W2[i];
    if (threadIdx.x < DE) sb1[threadIdx.x] = b1[threadIdx.x];
    if (threadIdx.x >= 128 && threadIdx.x < 128 + D) sb2[threadIdx.x - 128] = b2[threadIdx.x - 128];
    __syncthreads();

    const int e = blockIdx.x * 256 + threadIdx.x;
    const int s = senders[e];
    const int r = receivers[e];
    float edgef[DE];
    const float4* hr = reinterpret_cast<const float4*>(h + (size_t)r * D);
    const float4* hs = reinterpret_cast<const float4*>(h + (size_t)s * D);
    #pragma unroll
    for (int i = 0; i < 8; ++i) {
        float4 v = hr[i];
        edgef[4*i] = v.x; edgef[4*i+1] = v.y; edgef[4*i+2] = v.z; edgef[4*i+3] = v.w;
    }
    #pragma unroll
    for (int i = 0; i < 8; ++i) {
        float4 v = hs[i];
        edgef[D+4*i] = v.x; edgef[D+4*i+1] = v.y; edgef[D+4*i+2] = v.z; edgef[D+4*i+3] = v.w;
    }
    edgef[2*D] = coup[e < NCOUP ? e : e - NCOUP];
    float acc[D];
    #pragma unroll
    for (int d2 = 0; d2 < D; ++d2) acc[d2] = sb2[d2];
    for (int j = 0; j < DE; ++j) {
        const float* wrow = &sW1t[j * W1_LD];
        float p0 = 0.f, p1 = 0.f, p2 = 0.f, p3 = 0.f;
        #pragma unroll
        for (int k = 0; k < 64; k += 4) {
            p0 = fmaf(edgef[k], wrow[k], p0);
            p1 = fmaf(edgef[k+1], wrow[k+1], p1);
            p2 = fmaf(edgef[k+2], wrow[k+2], p2);
            p3 = fmaf(edgef[k+3], wrow[k+3], p3);
        }
        float hj = selu_f(sb1[j] + fmaf(edgef[64], wrow[64], (p0+p1)+(p2+p3)));
        const float* w2row = &sW2[j * D];
        #pragma unroll
        for (int d2 = 0; d2 < D; ++d2) acc[d2] = fmaf(hj, w2row[d2], acc[d2]);
    }
    float* op = out + (size_t)r * D;
    #pragma unroll
    for (int d2 = 0; d2 < D; ++d2) unsafeAtomicAdd(op + d2, selu_f(acc[d2]));
}

__global__ __launch_bounds__(256) void relu_kernel(float* __restrict__ out) {
    const int i = blockIdx.x * 256 + threadIdx.x;
    float4* p = reinterpret_cast<float4*>(out);
    float4 v = p[i];
    v.x = fmaxf(v.x, 0.f); v.y = fmaxf(v.y, 0.f);
    v.z = fmaxf(v.z, 0.f); v.w = fmaxf(v.w, 0.f);
    p[i] = v;
}

extern "C" void kernel_launch(void* const* d_in, const int* in_sizes, int n_in,
                              void* d_out, int out_size, void* d_ws, size_t ws_size,
                              hipStream_t stream) {
    const float* h    = (const float*)d_in[0];
    const float* coup = (const float*)d_in[1];
    const float* W1   = (const float*)d_in[2];
    const float* b1   = (const float*)d_in[3];
    const float* W2   = (const float*)d_in[4];
    const float* b2   = (const float*)d_in[5];
    // d_in[6..9] = Wq, bq, Wk, bk: unused — softmax over a size-1 axis is 1.0
    const int* senders   = (const int*)d_in[10];
    const int* receivers = (const int*)d_in[11];
    float* out = (float*)d_out;

    hipMemsetAsync(d_out, 0, (size_t)out_size * sizeof(float), stream);

    const size_t needA = (size_t)NNODES * JP * sizeof(float);
    if (ws_size >= 2 * needA) {
        float* A = (float*)d_ws;
        float* B = A + (size_t)NNODES * JP;
        node_precompute<<<(NNODES * JP + 255) / 256, 256, 0, stream>>>(h, W1, b1, A, B);
        edge_kernel<<<NEDGES / 256, 256, 0, stream>>>(
            A, B, coup, W1, W2, b2, senders, receivers, out);
    } else {
        edge_msg_fallback<<<NEDGES / 256, 256, 0, stream>>>(
            h, coup, W1, b1, W2, b2, senders, receivers, out);
    }
    relu_kernel<<<out_size / 4 / 256, 256, 0, stream>>>(out);
}